// Round 2
// baseline (508.492 us; speedup 1.0000x reference)
//
#include <hip/hip_runtime.h>

typedef short s16x8 __attribute__((ext_vector_type(8)));
typedef float f32x4 __attribute__((ext_vector_type(4)));

#define T_STEPS 128
#define BN_EPS 1e-5f

__device__ __forceinline__ unsigned short f2bf(float f) {
  unsigned u = __float_as_uint(f);
  u += 0x7FFFu + ((u >> 16) & 1u);   // round-to-nearest-even
  return (unsigned short)(u >> 16);
}
__device__ __forceinline__ float sigm(float x) {
  return __builtin_amdgcn_rcpf(1.0f + __expf(-x));
}
__device__ __forceinline__ float tanh_(float x) {
  // tanh(x) = 1 - 2/(exp(2x)+1); saturates correctly at +-inf
  return 1.0f - 2.0f * __builtin_amdgcn_rcpf(1.0f + __expf(2.0f * x));
}

// ---------------- per-timestep input moments: 5 scalars per t ----------------
__global__ void moments_kernel(const float* __restrict__ inp, float* __restrict__ mom, int B) {
  int t = blockIdx.x;
  int tid = threadIdx.x;
  float s0 = 0.f, s1 = 0.f, q0 = 0.f, q1 = 0.f, pp = 0.f;
  for (int b = tid; b < B; b += 256) {
    float2 x = *(const float2*)(inp + (size_t)b * (2 * T_STEPS) + 2 * t);
    s0 += x.x; s1 += x.y; q0 += x.x * x.x; q1 += x.y * x.y; pp += x.x * x.y;
  }
  float v[5] = {s0, s1, q0, q1, pp};
  #pragma unroll
  for (int i = 0; i < 5; ++i) {
    float x = v[i];
    #pragma unroll
    for (int o = 32; o > 0; o >>= 1) x += __shfl_down(x, o);
    v[i] = x;
  }
  __shared__ float red[4][5];
  if ((tid & 63) == 0) {
    #pragma unroll
    for (int i = 0; i < 5; ++i) red[tid >> 6][i] = v[i];
  }
  __syncthreads();
  if (tid == 0) {
    #pragma unroll
    for (int i = 0; i < 5; ++i)
      mom[t * 5 + i] = red[0][i] + red[1][i] + red[2][i] + red[3][i];
  }
}

// ------------- fold emb Linear+BN+ReLU into per-(t,j) affine coefs -----------
__global__ void fold_kernel(const float* __restrict__ mom,
                            const float* __restrict__ W_emb, const float* __restrict__ b_emb,
                            const float* __restrict__ gamma, const float* __restrict__ beta,
                            float* __restrict__ cA, float* __restrict__ cB, float* __restrict__ cC,
                            float invB) {
  int idx = blockIdx.x * 256 + threadIdx.x;   // t*128 + j
  if (idx >= T_STEPS * 128) return;
  int t = idx >> 7, j = idx & 127;
  float m0 = mom[t * 5 + 0] * invB, m1 = mom[t * 5 + 1] * invB;
  float q0 = mom[t * 5 + 2] * invB, q1 = mom[t * 5 + 3] * invB, p = mom[t * 5 + 4] * invB;
  float v00 = q0 - m0 * m0, v11 = q1 - m1 * m1, v01 = p - m0 * m1;
  float w0 = W_emb[2 * j], w1 = W_emb[2 * j + 1];
  float mu  = w0 * m0 + w1 * m1 + b_emb[j];
  float var = w0 * w0 * v00 + w1 * w1 * v11 + 2.f * w0 * w1 * v01;
  float a = gamma[j] * rsqrtf(var + BN_EPS);
  cA[idx] = a * w0;
  cB[idx] = a * w1;
  cC[idx] = beta[j] + a * (b_emb[j] - mu);
}

// ---------------- weights -> bf16 (gate matrix concat + W_out pad) -----------
__global__ void prepw_kernel(const float* __restrict__ Wih, const float* __restrict__ Whh,
                             const float* __restrict__ Wout,
                             unsigned short* __restrict__ Wb, unsigned short* __restrict__ Wob) {
  int idx = blockIdx.x * 256 + threadIdx.x;
  if (idx < 512 * 256) {
    int n = idx >> 8, k = idx & 255;
    float w = (k < 128) ? Wih[n * 128 + k] : Whh[n * 128 + (k - 128)];
    Wb[idx] = f2bf(w);
  } else if (idx < 512 * 256 + 16 * 128) {
    int i2 = idx - 512 * 256;
    int d = i2 >> 7, k = i2 & 127;
    Wob[i2] = (d < 5) ? f2bf(Wout[d * 128 + k]) : (unsigned short)0;
  }
}

// --------------------------- the recurrence ---------------------------------
// block: 512 thr (8 waves), 32 batch rows. X cols: [0,128) e | [128,256) h0 | [256,384) h1
__global__ __launch_bounds__(512, 2) void lstm_kernel(
    const float* __restrict__ inp,
    const float* __restrict__ cA, const float* __restrict__ cB, const float* __restrict__ cC,
    const unsigned short* __restrict__ Wb, const unsigned short* __restrict__ Wob,
    const float* __restrict__ bih, const float* __restrict__ bhh,
    float* __restrict__ outz, float* __restrict__ hout, float* __restrict__ cout) {
  __shared__ __align__(16) short X[32][392];   // 392 = 384 + 8 pad (row = 196 dw, 196%32=4 -> conflict-free b128)

  const int tid  = threadIdx.x;
  const int wave = tid >> 6;
  const int lane = tid & 63;
  const int l15  = lane & 15;
  const int lk   = lane >> 4;        // 0..3
  const int b0   = blockIdx.x * 32;
  const int em   = tid >> 4;         // e row 0..31
  const int ecg  = tid & 15;         // e col group

  // --- weights to registers (once). wave owns cols [16w,16w+16) of each gate.
  s16x8 wfrag[4][8];
  #pragma unroll
  for (int g = 0; g < 4; ++g)
    #pragma unroll
    for (int kk = 0; kk < 8; ++kk)
      wfrag[g][kk] = *(const s16x8*)(Wb + (size_t)(g * 128 + wave * 16 + l15) * 256 + kk * 32 + lk * 8);
  s16x8 wof[4];
  #pragma unroll
  for (int kk = 0; kk < 4; ++kk)
    wof[kk] = *(const s16x8*)(Wob + l15 * 128 + kk * 32 + lk * 8);
  float biasg[4];
  #pragma unroll
  for (int g = 0; g < 4; ++g) {
    int n = g * 128 + wave * 16 + l15;
    biasg[g] = bih[n] + bhh[n];
  }

  float creg[2][4] = {{0.f,0.f,0.f,0.f},{0.f,0.f,0.f,0.f}};
  float hreg[2][4] = {{0.f,0.f,0.f,0.f},{0.f,0.f,0.f,0.f}};

  auto do_e = [&](int tn) {
    float2 xv = *(const float2*)(inp + (size_t)(b0 + em) * (2 * T_STEPS) + 2 * tn);
    const float4* pa = (const float4*)(cA + tn * 128 + ecg * 8);
    const float4* pb = (const float4*)(cB + tn * 128 + ecg * 8);
    const float4* pc = (const float4*)(cC + tn * 128 + ecg * 8);
    s16x8 ev;
    #pragma unroll
    for (int q = 0; q < 2; ++q) {
      float4 va = pa[q], vb = pb[q], vc = pc[q];
      float e0 = fmaxf(0.f, vc.x + va.x * xv.x + vb.x * xv.y);
      float e1 = fmaxf(0.f, vc.y + va.y * xv.x + vb.y * xv.y);
      float e2 = fmaxf(0.f, vc.z + va.z * xv.x + vb.z * xv.y);
      float e3 = fmaxf(0.f, vc.w + va.w * xv.x + vb.w * xv.y);
      ev[4 * q + 0] = (short)f2bf(e0);
      ev[4 * q + 1] = (short)f2bf(e1);
      ev[4 * q + 2] = (short)f2bf(e2);
      ev[4 * q + 3] = (short)f2bf(e3);
    }
    *(s16x8*)&X[em][ecg * 8] = ev;
  };

  // zero h-buffer0; e(0)
  {
    s16x8 z = {0,0,0,0,0,0,0,0};
    *(s16x8*)&X[em][128 + ecg * 8] = z;
  }
  do_e(0);
  __syncthreads();

  #pragma unroll 1
  for (int t = 0; t < T_STEPS; ++t) {
    const int rb = 128 + (t & 1) * 128;         // MFMA reads h from here
    const int wb = 128 + ((t + 1) & 1) * 128;   // update writes h here
    f32x4 acc[2][4];
    #pragma unroll
    for (int mf = 0; mf < 2; ++mf)
      #pragma unroll
      for (int g = 0; g < 4; ++g) {
        f32x4 v = {biasg[g], biasg[g], biasg[g], biasg[g]};
        acc[mf][g] = v;
      }
    #pragma unroll
    for (int kk = 0; kk < 8; ++kk) {
      const int coff = (kk < 4) ? (kk * 32 + lk * 8) : (rb + (kk - 4) * 32 + lk * 8);
      s16x8 a0 = *(const s16x8*)&X[l15][coff];
      s16x8 a1 = *(const s16x8*)&X[16 + l15][coff];
      #pragma unroll
      for (int g = 0; g < 4; ++g) {
        acc[0][g] = __builtin_amdgcn_mfma_f32_16x16x32_bf16(a0, wfrag[g][kk], acc[0][g], 0, 0, 0);
        acc[1][g] = __builtin_amdgcn_mfma_f32_16x16x32_bf16(a1, wfrag[g][kk], acc[1][g], 0, 0, 0);
      }
    }
    // pointwise LSTM update; lane owns rows {lk*4+r, +16}, col wave*16+l15
    #pragma unroll
    for (int mf = 0; mf < 2; ++mf)
      #pragma unroll
      for (int r = 0; r < 4; ++r) {
        float gi = sigm(acc[mf][0][r]);
        float gf = sigm(acc[mf][1][r]);
        float gg = tanh_(acc[mf][2][r]);
        float go = sigm(acc[mf][3][r]);
        float cc = gf * creg[mf][r] + gi * gg;
        creg[mf][r] = cc;
        float hh = go * tanh_(cc);
        hreg[mf][r] = hh;
        X[mf * 16 + lk * 4 + r][wb + wave * 16 + l15] = (short)f2bf(hh);
      }
    __syncthreads();
    // z = h_new @ W_out^T  (waves 0,1; 16 rows each)
    if (wave < 2) {
      f32x4 zac = {0.f, 0.f, 0.f, 0.f};
      #pragma unroll
      for (int kk = 0; kk < 4; ++kk) {
        s16x8 a = *(const s16x8*)&X[wave * 16 + l15][wb + kk * 32 + lk * 8];
        zac = __builtin_amdgcn_mfma_f32_16x16x32_bf16(a, wof[kk], zac, 0, 0, 0);
      }
      if (l15 < 5) {
        #pragma unroll
        for (int r = 0; r < 4; ++r) {
          int m = wave * 16 + lk * 4 + r;
          outz[((size_t)(b0 + m) * T_STEPS + t) * 5 + l15] = zac[r];
        }
      }
    }
    if (t < T_STEPS - 1) do_e(t + 1);
    __syncthreads();
  }

  // final h, c (fp32 values)
  #pragma unroll
  for (int mf = 0; mf < 2; ++mf)
    #pragma unroll
    for (int r = 0; r < 4; ++r) {
      int m = mf * 16 + lk * 4 + r;
      size_t base = (size_t)(b0 + m) * 128 + wave * 16 + l15;
      hout[base] = hreg[mf][r];
      cout[base] = creg[mf][r];
    }
}

// ---------------- deferred output BN: stats then normalize -------------------
__global__ void stats_kernel(const float* __restrict__ z, float* __restrict__ stats,
                             const float* __restrict__ gamma, const float* __restrict__ beta, int B) {
  int grp = blockIdx.x;           // t*5 + d
  int d = grp % 5;
  int tid = threadIdx.x;
  float s = 0.f, q = 0.f;
  for (int b = tid; b < B; b += 256) {
    float v = z[(size_t)b * (T_STEPS * 5) + grp];
    s += v; q += v * v;
  }
  #pragma unroll
  for (int o = 32; o > 0; o >>= 1) { s += __shfl_down(s, o); q += __shfl_down(q, o); }
  __shared__ float rs[4], rq[4];
  if ((tid & 63) == 0) { rs[tid >> 6] = s; rq[tid >> 6] = q; }
  __syncthreads();
  if (tid == 0) {
    s = rs[0] + rs[1] + rs[2] + rs[3];
    q = rq[0] + rq[1] + rq[2] + rq[3];
    float mean = s / (float)B;
    float var  = q / (float)B - mean * mean;
    float sc = gamma[d] * rsqrtf(var + BN_EPS);
    stats[grp * 2 + 0] = sc;
    stats[grp * 2 + 1] = beta[d] - mean * sc;   // b_out cancels inside BN
  }
}

__global__ void norm_kernel(float* __restrict__ z, const float* __restrict__ stats, int n) {
  int i = blockIdx.x * 512 + threadIdx.x;
  if (i < n) {
    int grp = i % (T_STEPS * 5);
    float2 st = *(const float2*)(stats + grp * 2);
    z[i] = z[i] * st.x + st.y;
  }
}

extern "C" void kernel_launch(void* const* d_in, const int* in_sizes, int n_in,
                              void* d_out, int out_size, void* d_ws, size_t ws_size,
                              hipStream_t stream) {
  const float* inp    = (const float*)d_in[0];
  const float* W_emb  = (const float*)d_in[1];
  const float* b_emb  = (const float*)d_in[2];
  const float* g_emb  = (const float*)d_in[3];
  const float* be_emb = (const float*)d_in[4];
  const float* Wih    = (const float*)d_in[5];
  const float* bih    = (const float*)d_in[6];
  const float* Whh    = (const float*)d_in[7];
  const float* bhh    = (const float*)d_in[8];
  const float* Wout   = (const float*)d_in[9];
  // d_in[10] = b_out: cancels inside the output BatchNorm
  const float* g_out  = (const float*)d_in[11];
  const float* be_out = (const float*)d_in[12];

  const int B = in_sizes[0] / (2 * T_STEPS);   // 8192

  char* ws = (char*)d_ws;
  float*          mom   = (float*)(ws + 0);          //  2560 B
  float*          cA    = (float*)(ws + 4096);       // 64 KB
  float*          cB    = (float*)(ws + 69632);
  float*          cC    = (float*)(ws + 135168);
  unsigned short* Wb    = (unsigned short*)(ws + 200704);  // 256 KB bf16 [512][256]
  unsigned short* Wob   = (unsigned short*)(ws + 462848);  // 4 KB bf16 [16][128]
  float*          stats = (float*)(ws + 466944);     // 5120 B

  float* outz = (float*)d_out;                       // [B][T][5] raw z, normalized in-place
  float* hout = outz + (size_t)B * T_STEPS * 5;
  float* cout = hout + (size_t)B * 128;

  moments_kernel<<<T_STEPS, 256, 0, stream>>>(inp, mom, B);
  fold_kernel<<<(T_STEPS * 128 + 255) / 256, 256, 0, stream>>>(mom, W_emb, b_emb, g_emb, be_emb,
                                                               cA, cB, cC, 1.0f / (float)B);
  prepw_kernel<<<(512 * 256 + 16 * 128 + 255) / 256, 256, 0, stream>>>(Wih, Whh, Wout, Wb, Wob);
  lstm_kernel<<<B / 32, 512, 0, stream>>>(inp, cA, cB, cC, Wb, Wob, bih, bhh, outz, hout, cout);
  stats_kernel<<<T_STEPS * 5, 256, 0, stream>>>(outz, stats, g_out, be_out, B);
  const int n = B * T_STEPS * 5;
  norm_kernel<<<(n + 511) / 512, 512, 0, stream>>>(outz, stats, n);
}